// Round 14
// baseline (395.009 us; speedup 1.0000x reference)
//
#include <hip/hip_runtime.h>
#include <hip/hip_bf16.h>
#include <cstdint>
#include <cstddef>

// Problem constants
#define NB 32
#define NL 2048
#define NH 1024
#define NK 1280

typedef __bf16 bf16x8 __attribute__((ext_vector_type(8)));
typedef short short8 __attribute__((ext_vector_type(8)));
typedef float f32x4 __attribute__((ext_vector_type(4)));
typedef unsigned short u16x4 __attribute__((ext_vector_type(4)));
typedef unsigned short u16x8 __attribute__((ext_vector_type(8)));

__device__ __forceinline__ float bfbits2f(unsigned short b) {
    union { unsigned int u; float f; } v;
    v.u = ((unsigned int)b) << 16;
    return v.f;
}

__device__ __forceinline__ void load_lds16(const void* g, void* l) {
    __builtin_amdgcn_global_load_lds((const __attribute__((address_space(1))) void*)g,
                                     (__attribute__((address_space(3))) void*)l, 16, 0, 0);
}

// ---------------- K0: fused cvt — keys fp32->bf16 + W2_w fp32->bf16 ----------------
__global__ __launch_bounds__(256) void k_cvt(const float* __restrict__ keys,
                                             unsigned short* __restrict__ kb,
                                             const float* __restrict__ w2,
                                             unsigned short* __restrict__ w2b) {
    const int bid = blockIdx.x;
    if (bid < 40960) {
        size_t i = ((size_t)bid * 256 + threadIdx.x) * 8;
        f32x4 v0 = *(const f32x4*)(keys + i);
        f32x4 v1 = *(const f32x4*)(keys + i + 4);
        u16x8 o;
#pragma unroll
        for (int c = 0; c < 4; ++c) {
            o[c] = __builtin_bit_cast(unsigned short, (__bf16)v0[c]);
            o[c + 4] = __builtin_bit_cast(unsigned short, (__bf16)v1[c]);
        }
        *(u16x8*)(kb + i) = o;
    } else {
        int i = ((bid - 40960) * 256 + threadIdx.x) * 4;
        f32x4 v = *(const f32x4*)(w2 + i);
        u16x4 o;
#pragma unroll
        for (int c = 0; c < 4; ++c) o[c] = __builtin_bit_cast(unsigned short, (__bf16)v[c]);
        *(u16x4*)(w2b + i) = o;
    }
}

__global__ __launch_bounds__(256) void k_w2cvt(const float* __restrict__ w2,
                                               unsigned short* __restrict__ w2b) {
    int i = (blockIdx.x * 256 + threadIdx.x) * 4;
    f32x4 v = *(const f32x4*)(w2 + i);
    u16x4 o;
#pragma unroll
    for (int c = 0; c < 4; ++c) o[c] = __builtin_bit_cast(unsigned short, (__bf16)v[c]);
    *(u16x4*)(w2b + i) = o;
}

// ---------------- K1: hidden ----------------
__global__ __launch_bounds__(256) void k_hidden(const float* __restrict__ q,
                                                const float* __restrict__ w1,
                                                const float* __restrict__ w1b,
                                                const float* __restrict__ w2b,
                                                float* __restrict__ hidden) {
    const int t = threadIdx.x;
    const int h = blockIdx.x;
    __shared__ __align__(16) float w[1024];
    __shared__ float red[256];
    *(f32x4*)&w[t * 4] = *(const f32x4*)(w1 + (size_t)h * 1024 + t * 4);
    __syncthreads();
    const int b = t & 31, seg = t >> 5;
    const f32x4* q4 = (const f32x4*)(q + (size_t)b * 1024 + seg * 128);
    f32x4 accv = (f32x4){0.f, 0.f, 0.f, 0.f};
#pragma unroll 4
    for (int i = 0; i < 32; ++i) {
        f32x4 qv = q4[i];
        f32x4 wv = *(f32x4*)&w[seg * 128 + i * 4];
#pragma unroll
        for (int c = 0; c < 4; ++c) accv[c] = fmaf(qv[c], wv[c], accv[c]);
    }
    red[t] = accv[0] + accv[1] + accv[2] + accv[3];
    __syncthreads();
    if (t < 32) {
        float tot = 0.f;
#pragma unroll
        for (int sg = 0; sg < 8; ++sg) tot += red[sg * 32 + t];
        hidden[(size_t)t * 1024 + h] = tot + w1b[h] + w2b[h];
    }
}

// ---------------- K2: 128x128 tile, BK=64, r9 staging/swizzle, 2 blocks/CU ----------------
// 4 waves (2M x 2N), per-wave 64x64 (acc[4][4] = 64 regs). LDS: 2 K-tile dbuf x
// (A 16KB + B 16KB) = 64KB + 1KB sred -> 2 resident blocks/CU: the per-tile
// vmcnt(0) drain stalls only one 4-wave block while the co-resident block's
// MFMA feeds the matrix pipe (m114 cross-block overlap; m103: 128^2=912 TF >
// 256^2=792 at this structure class). Staging chunk = 8 rows x 128B: lane l
// fetches row j*8+(l>>3) of wave's 32-row band, seg (l&7)^(l>>3) -> 8 cache
// lines/instr, linear LDS dest. ds_read: elem = buf*8192 + row*64 +
// (((ks*4+pl)^(row&7))*8) — same involution, uniform banks. One
// vmcnt(0)+barrier per K-tile. grid 4096 (512 rt x 8 ht), block 256.
__global__ __launch_bounds__(256) void k_score_bf(const unsigned short* __restrict__ keysbf,
                                                  const unsigned short* __restrict__ w2bf,
                                                  const float* __restrict__ hidden,
                                                  const float* __restrict__ va,
                                                  float* __restrict__ spart) {
    __shared__ __align__(16) __bf16 As[16384];  // 2 x [128][64] = 32KB
    __shared__ __align__(16) __bf16 Bs[16384];  // 32KB
    __shared__ float sred[256];                 // [128 rows][2 wc]

    const int t = threadIdx.x;
    const int lane = t & 63, wid = t >> 6;
    const int wr = wid >> 1, wc = wid & 1;
    const int pl = lane >> 4, r0 = lane & 15;

    // Bijective XCD swizzle, nwg=4096 (%8==0): XCD x owns rt in [x*64,(x+1)*64),
    // ht fastest (full w2bf + A-panel L2 reuse per XCD).
    const int bid = blockIdx.x;
    const int v = (bid & 7) * 512 + (bid >> 3);
    const int rt = v >> 3;  // 512 row tiles (128 rows each; 16 tiles/batch)
    const int ht = v & 7;   // 8 col tiles (128 h each)

    // Epilogue constants loaded first (oldest vmem, drained by prologue vmcnt).
    const int b = rt >> 4;
    float hv[4], vav[4];
#pragma unroll
    for (int n = 0; n < 4; ++n) {
        int h = ht * 128 + wc * 64 + n * 16 + r0;
        hv[n] = hidden[(size_t)b * 1024 + h];
        vav[n] = va[h];
    }

    // ---- Staging addressing (coalesced): wave wid stages rows wid*32..+31.
    const int srow = wid * 32 + (lane >> 3);               // row within tile (j=0)
    const int sseg = (lane & 7) ^ ((lane >> 3) & 7);       // pre-swizzled 16B segment
    const unsigned short* pA = keysbf + (size_t)(rt * 128 + srow) * 1280 + sseg * 8;
    const unsigned short* pB = w2bf + (size_t)(ht * 128 + srow) * 1280 + sseg * 8;
    const int sdst = wid * 4096 + lane * 16;               // byte offset, + j*1024

    // ---- ds_read: element = BUF*8192 + row*64 + slot(ks)*8,
    // slot(ks) = ((ks*4+pl) ^ (row&7)); row&7 == r0&7 for all fragments.
    const int r7 = r0 & 7;
    const int sw0 = ((0 * 4 + pl) ^ r7) * 8;
    const int sw1 = ((1 * 4 + pl) ^ r7) * 8;
    const int aBase = (wr * 64 + r0) * 64;
    const int bBase = (wc * 64 + r0) * 64;

    f32x4 acc[4][4];
#pragma unroll
    for (int m = 0; m < 4; ++m)
#pragma unroll
        for (int n = 0; n < 4; ++n) acc[m][n] = (f32x4){0.f, 0.f, 0.f, 0.f};

    // NXT = buffer (0/1) in 16KB byte units; KOFF = k-tile element offset.
#define ST_A(NXT, KOFF)                                                              \
    do {                                                                             \
        _Pragma("unroll") for (int j = 0; j < 4; ++j)                                \
            load_lds16(pA + (KOFF) + j * (8 * 1280),                                 \
                       (char*)As + (NXT) * 16384 + sdst + j * 1024);                 \
    } while (0)
#define ST_B(NXT, KOFF)                                                              \
    do {                                                                             \
        _Pragma("unroll") for (int j = 0; j < 4; ++j)                                \
            load_lds16(pB + (KOFF) + j * (8 * 1280),                                 \
                       (char*)Bs + (NXT) * 16384 + sdst + j * 1024);                 \
    } while (0)

#define RD_B(DST, CUR, KS)                                                           \
    _Pragma("unroll") for (int n = 0; n < 4; ++n)                                    \
        DST[n] = *(bf16x8*)&Bs[(CUR) * 8192 + bBase + n * 1024 + ((KS) ? sw1 : sw0)];
#define RD_A(DST, CUR, KS)                                                           \
    _Pragma("unroll") for (int mm = 0; mm < 4; ++mm)                                 \
        DST[mm] = *(bf16x8*)&As[(CUR) * 8192 + aBase + mm * 1024 + ((KS) ? sw1 : sw0)];
#define MM(AV, BV)                                                                   \
    do {                                                                             \
        __builtin_amdgcn_s_setprio(1);                                               \
        _Pragma("unroll") for (int mm = 0; mm < 4; ++mm)                             \
            _Pragma("unroll") for (int n = 0; n < 4; ++n)                            \
                acc[mm][n] = __builtin_amdgcn_mfma_f32_16x16x32_bf16(                \
                    AV[mm], BV[n], acc[mm][n], 0, 0, 0);                             \
        __builtin_amdgcn_s_setprio(0);                                               \
    } while (0)

    // One K-tile, single trailing vmcnt(0)+barrier. Interior compiler-scheduled.
#define TILE(CUR, NXT, KOFF, DOST, LAST)                                             \
    do {                                                                             \
        if (DOST) ST_A(NXT, KOFF);                                                   \
        bf16x8 b0v[4], a0v[4];                                                       \
        RD_B(b0v, CUR, 0);                                                           \
        RD_A(a0v, CUR, 0);                                                           \
        MM(a0v, b0v);                                                                \
        if (DOST) ST_B(NXT, KOFF);                                                   \
        bf16x8 b1v[4], a1v[4];                                                       \
        RD_B(b1v, CUR, 1);                                                           \
        RD_A(a1v, CUR, 1);                                                           \
        MM(a1v, b1v);                                                                \
        if (!(LAST)) {                                                               \
            asm volatile("s_waitcnt vmcnt(0)" ::: "memory");                         \
            __builtin_amdgcn_s_barrier();                                            \
        }                                                                            \
    } while (0)

    // Prologue: stage T0 fully, drain, publish.
    ST_A(0, 0);
    ST_B(0, 0);
    asm volatile("s_waitcnt vmcnt(0)" ::: "memory");
    __builtin_amdgcn_s_barrier();

    int koff = 64;  // element offset of the tile being staged (kt*64)
    for (int t2 = 0; t2 < 9; ++t2) {
        TILE(0, 1, koff, 1, 0);
        koff += 64;
        TILE(1, 0, koff, 1, 0);
        koff += 64;
    }
    TILE(0, 1, koff, 1, 0);  // tile 18, stages T19 (koff = 19*64)
    TILE(1, 0, 0, 0, 1);     // tile 19: no staging, no trailing sync
#undef TILE
#undef MM
#undef RD_A
#undef RD_B
#undef ST_A
#undef ST_B

    // Epilogue: relu(enc + hidden')*Va, reduce over this tile's 128 h.
#pragma unroll
    for (int m = 0; m < 4; ++m) {
#pragma unroll
        for (int j = 0; j < 4; ++j) {
            float s = 0.f;
#pragma unroll
            for (int n = 0; n < 4; ++n) {
                float v2 = acc[m][n][j] + hv[n];  // C/D: col=lane&15, row=(lane>>4)*4+j
                v2 = fmaxf(v2, 0.f);
                s = fmaf(v2, vav[n], s);
            }
            s += __shfl_xor(s, 1);
            s += __shfl_xor(s, 2);
            s += __shfl_xor(s, 4);
            s += __shfl_xor(s, 8);
            if (r0 == 0) sred[(wr * 64 + m * 16 + pl * 4 + j) * 2 + wc] = s;
        }
    }
    __syncthreads();
    if (t < 128) spart[(size_t)ht * 65536 + rt * 128 + t] = sred[t * 2] + sred[t * 2 + 1];
}

// ---------------- K2 fallback (fp32 keys, round-1 structure, 8 ht partials) ----------------
#define LOAD_AB(IT)                                        \
    do {                                                   \
        const float* ap_ = aptr + (IT) * 32;               \
        a0 = *(const f32x4*)(ap_);                         \
        a1 = *(const f32x4*)(ap_ + 4);                     \
        a2 = *(const f32x4*)(ap_ + 8);                     \
        a3 = *(const f32x4*)(ap_ + 12);                    \
        const unsigned short* bp_ = bptr + (IT) * 32;      \
        b0 = *(const short8*)(bp_);                        \
        b1 = *(const short8*)(bp_ + 8);                    \
    } while (0)

__global__ __launch_bounds__(256, 2) void k_score_f32(const float* __restrict__ keys,
                                                      const unsigned short* __restrict__ w2bf,
                                                      const float* __restrict__ hidden,
                                                      const float* __restrict__ va,
                                                      float* __restrict__ spart) {
    __shared__ __align__(16) __bf16 As[4096];
    __shared__ __align__(16) __bf16 Bs[4096];
    __shared__ float sred[256];
    const int t = threadIdx.x;
    const int rt = blockIdx.x, ht = blockIdx.y;
    const int row = t >> 1, half = t & 1;
    const float* aptr = keys + (size_t)(rt * 128 + row) * 1280 + half * 16;
    const unsigned short* bptr = w2bf + (size_t)(ht * 128 + row) * 1280 + half * 16;
    const int wA0 = (2 * half) * 1024 + row * 8;
    const int wA1 = wA0 + 1024;
    f32x4 acc[4][4];
#pragma unroll
    for (int m = 0; m < 4; ++m)
#pragma unroll
        for (int n = 0; n < 4; ++n) acc[m][n] = (f32x4){0.f, 0.f, 0.f, 0.f};
    const int lane = t & 63, wid = t >> 6;
    const int wr = wid >> 1, wc = wid & 1;
    const int pl = lane >> 4, r0 = lane & 15;
    const int aroff = pl * 1024 + (wr * 64 + r0) * 8;
    const int broff = pl * 1024 + (wc * 64 + r0) * 8;
    f32x4 a0, a1, a2, a3;
    short8 b0, b1;
    LOAD_AB(0);
    for (int it = 0; it < 40; ++it) {
        __syncthreads();
        bf16x8 p0, p1;
#pragma unroll
        for (int e = 0; e < 4; ++e) {
            p0[e] = (__bf16)a0[e];
            p0[e + 4] = (__bf16)a1[e];
            p1[e] = (__bf16)a2[e];
            p1[e + 4] = (__bf16)a3[e];
        }
        *(bf16x8*)&As[wA0] = p0;
        *(bf16x8*)&As[wA1] = p1;
        *(short8*)&Bs[wA0] = b0;
        *(short8*)&Bs[wA1] = b1;
        __syncthreads();
        if (it + 1 < 40) LOAD_AB(it + 1);
        bf16x8 af[4], bfv[4];
#pragma unroll
        for (int m = 0; m < 4; ++m) af[m] = *(bf16x8*)&As[aroff + m * 128];
#pragma unroll
        for (int n = 0; n < 4; ++n) bfv[n] = *(bf16x8*)&Bs[broff + n * 128];
#pragma unroll
        for (int m = 0; m < 4; ++m)
#pragma unroll
            for (int n = 0; n < 4; ++n)
                acc[m][n] = __builtin_amdgcn_mfma_f32_16x16x32_bf16(af[m], bfv[n], acc[m][n], 0, 0, 0);
    }
    const int b = rt >> 4;
    float hv[4], vav[4];
#pragma unroll
    for (int n = 0; n < 4; ++n) {
        int h = ht * 128 + wc * 64 + n * 16 + r0;
        hv[n] = hidden[(size_t)b * 1024 + h];
        vav[n] = va[h];
    }
#pragma unroll
    for (int m = 0; m < 4; ++m) {
#pragma unroll
        for (int j = 0; j < 4; ++j) {
            float s = 0.f;
#pragma unroll
            for (int n = 0; n < 4; ++n) {
                float v = acc[m][n][j] + hv[n];
                v = fmaxf(v, 0.f);
                s = fmaf(v, vav[n], s);
            }
            s += __shfl_xor(s, 1);
            s += __shfl_xor(s, 2);
            s += __shfl_xor(s, 4);
            s += __shfl_xor(s, 8);
            if (r0 == 0) sred[(wr * 64 + m * 16 + pl * 4 + j) * 2 + wc] = s;
        }
    }
    __syncthreads();
    if (t < 128) spart[(size_t)ht * 65536 + rt * 128 + t] = sred[t * 2] + sred[t * 2 + 1];
}

// ---------------- K3: softmax (8 partials) ----------------
__global__ __launch_bounds__(256) void k_softmax8(const float* __restrict__ spart,
                                                  float* __restrict__ wout) {
    const int b = blockIdx.x, t = threadIdx.x;
    __shared__ float red[256];
    float s[8];
#pragma unroll
    for (int i = 0; i < 8; ++i) {
        int l = t + i * 256;
        float v = 0.f;
#pragma unroll
        for (int ht = 0; ht < 8; ++ht) v += spart[(size_t)ht * 65536 + b * 2048 + l];
        s[i] = v;
    }
    float mx = s[0];
#pragma unroll
    for (int i = 1; i < 8; ++i) mx = fmaxf(mx, s[i]);
    red[t] = mx;
    __syncthreads();
    for (int st = 128; st > 0; st >>= 1) {
        if (t < st) red[t] = fmaxf(red[t], red[t + st]);
        __syncthreads();
    }
    mx = red[0];
    __syncthreads();
    float e[8];
    float sum = 0.f;
#pragma unroll
    for (int i = 0; i < 8; ++i) {
        e[i] = __expf(s[i] - mx);
        sum += e[i];
    }
    red[t] = sum;
    __syncthreads();
    for (int st = 128; st > 0; st >>= 1) {
        if (t < st) red[t] += red[t + st];
        __syncthreads();
    }
    float inv = 1.0f / red[0];
#pragma unroll
    for (int i = 0; i < 8; ++i) wout[(size_t)b * 2048 + t + i * 256] = e[i] * inv;
}

// ---------------- K4 (bf16): context partials ----------------
__global__ __launch_bounds__(256) void k_ctx_bf(const unsigned short* __restrict__ keysbf,
                                                const float* __restrict__ wts,
                                                float* __restrict__ cpart) {
    const int b = blockIdx.x, kc = blockIdx.y, lc = blockIdx.z, t = threadIdx.x;
    const int c = t & 15, g = t >> 4;
    const unsigned short* kp = keysbf + ((size_t)b * 2048 + lc * 512 + g) * 1280 + kc * 128 + c * 8;
    const float* wb = wts + (size_t)b * 2048 + lc * 512 + g;
    float acc[8];
#pragma unroll
    for (int j = 0; j < 8; ++j) acc[j] = 0.f;
    for (int i = 0; i < 32; ++i) {
        u16x8 v = *(const u16x8*)kp;
        float w = *wb;
#pragma unroll
        for (int j = 0; j < 8; ++j) acc[j] = fmaf(w, bfbits2f(v[j]), acc[j]);
        kp += (size_t)16 * 1280;
        wb += 16;
    }
    __shared__ float sred[2048];
#pragma unroll
    for (int j = 0; j < 8; ++j) sred[t * 8 + j] = acc[j];
    __syncthreads();
    if (t < 128) {
        float s = 0.f;
#pragma unroll
        for (int g2 = 0; g2 < 16; ++g2) s += sred[g2 * 128 + t];
        cpart[((size_t)lc * 32 + b) * 1280 + kc * 128 + t] = s;
    }
}

__global__ __launch_bounds__(256) void k_ctxred4(const float* __restrict__ cpart,
                                                 float* __restrict__ ctx) {
    const int idx = blockIdx.x * 256 + threadIdx.x;  // < 40960
    const int b = idx / 1280, k = idx % 1280;
    float s = 0.f;
#pragma unroll
    for (int lc = 0; lc < 4; ++lc) s += cpart[((size_t)lc * 32 + b) * 1280 + k];
    ctx[(size_t)b * 1280 + k] = s;
}

// ---------------- K4/K5 fallback (fp32 keys) ----------------
__global__ __launch_bounds__(256) void k_ctxpart_f32(const float* __restrict__ keys,
                                                     const float* __restrict__ wts,
                                                     float* __restrict__ cpart) {
    const int b = blockIdx.x, lc = blockIdx.y, t = threadIdx.x;
    f32x4 acc0 = (f32x4){0.f, 0.f, 0.f, 0.f};
    f32x4 acc1 = (f32x4){0.f, 0.f, 0.f, 0.f};
    const int l0 = lc * 128;
    const float* kb = keys + ((size_t)b * 2048 + l0) * 1280;
    const float* wb = wts + (size_t)b * 2048 + l0;
    for (int l = 0; l < 128; ++l) {
        float w = wb[l];
        const f32x4* kr = (const f32x4*)(kb + (size_t)l * 1280);
        f32x4 v = kr[t];
#pragma unroll
        for (int ci = 0; ci < 4; ++ci) acc0[ci] = fmaf(v[ci], w, acc0[ci]);
        if (t < 64) {
            f32x4 v2 = kr[256 + t];
#pragma unroll
            for (int ci = 0; ci < 4; ++ci) acc1[ci] = fmaf(v2[ci], w, acc1[ci]);
        }
    }
    float* cp = cpart + ((size_t)lc * 32 + b) * 1280;
    *(f32x4*)(cp + 4 * t) = acc0;
    if (t < 64) *(f32x4*)(cp + 1024 + 4 * t) = acc1;
}

__global__ __launch_bounds__(256) void k_ctxred16(const float* __restrict__ cpart,
                                                  float* __restrict__ ctx) {
    const int idx = blockIdx.x * 256 + threadIdx.x;
    const int b = idx / 1280, k = idx % 1280;
    float s = 0.f;
#pragma unroll
    for (int lc = 0; lc < 16; ++lc) s += cpart[((size_t)lc * 32 + b) * 1280 + k];
    ctx[(size_t)b * 1280 + k] = s;
}

extern "C" void kernel_launch(void* const* d_in, const int* in_sizes, int n_in,
                              void* d_out, int out_size, void* d_ws, size_t ws_size,
                              hipStream_t stream) {
    const float* query = (const float*)d_in[0];
    const float* keys = (const float*)d_in[1];
    const float* W1_w = (const float*)d_in[2];
    const float* W1_b = (const float*)d_in[3];
    const float* W2_w = (const float*)d_in[4];
    const float* W2_b = (const float*)d_in[5];
    const float* Va_w = (const float*)d_in[6];
    // Va_b cancels in softmax.

    float* out = (float*)d_out;
    float* ctx = out;            // [32][1280]
    float* wts = out + NB * NK;  // [32][2048]

    char* ws = (char*)d_ws;
    float* hidden = (float*)ws;                             // 131072 B
    unsigned short* w2bf = (unsigned short*)(ws + 131072);  // 2621440 B
    float* spart = (float*)(ws + 2752512);                  // 2097152 B
    float* cpart = (float*)(ws + 4849664);                  // <= 2621440 B
    unsigned short* keysbf = (unsigned short*)(ws + 7471104);  // 167772160 B
    const bool big = ws_size >= (size_t)7471104 + 167772160;

    if (big) {
        k_cvt<<<42240, 256, 0, stream>>>(keys, keysbf, W2_w, w2bf);
        k_hidden<<<1024, 256, 0, stream>>>(query, W1_w, W1_b, W2_b, hidden);
        k_score_bf<<<4096, 256, 0, stream>>>(keysbf, w2bf, hidden, Va_w, spart);
        k_softmax8<<<32, 256, 0, stream>>>(spart, wts);
        k_ctx_bf<<<dim3(32, 10, 4), 256, 0, stream>>>(keysbf, wts, cpart);
        k_ctxred4<<<160, 256, 0, stream>>>(cpart, ctx);
    } else {
        k_w2cvt<<<1280, 256, 0, stream>>>(W2_w, w2bf);
        k_hidden<<<1024, 256, 0, stream>>>(query, W1_w, W1_b, W2_b, hidden);
        k_score_f32<<<dim3(512, 8), 256, 0, stream>>>(keys, w2bf, hidden, Va_w, spart);
        k_softmax8<<<32, 256, 0, stream>>>(spart, wts);
        k_ctxpart_f32<<<dim3(32, 16), 256, 0, stream>>>(keys, wts, cpart);
        k_ctxred16<<<160, 256, 0, stream>>>(cpart, ctx);
    }
}

// Round 15
// 367.960 us; speedup vs baseline: 1.0735x; 1.0735x over previous
//
#include <hip/hip_runtime.h>
#include <hip/hip_bf16.h>
#include <cstdint>
#include <cstddef>

// Problem constants
#define NB 32
#define NL 2048
#define NH 1024
#define NK 1280

typedef __bf16 bf16x8 __attribute__((ext_vector_type(8)));
typedef short short8 __attribute__((ext_vector_type(8)));
typedef float f32x4 __attribute__((ext_vector_type(4)));
typedef unsigned short u16x4 __attribute__((ext_vector_type(4)));
typedef unsigned short u16x8 __attribute__((ext_vector_type(8)));

__device__ __forceinline__ void load_lds16(const void* g, void* l) {
    __builtin_amdgcn_global_load_lds((const __attribute__((address_space(1))) void*)g,
                                     (__attribute__((address_space(3))) void*)l, 16, 0, 0);
}

__device__ __forceinline__ unsigned short bfbits(float x) {
    __bf16 b = (__bf16)x;
    return __builtin_bit_cast(unsigned short, b);
}

// ---------------- K0: prep — W2_w fp32->bf16 (blocks 0..1279) + hidden (1280..2303) ----------------
// hidden[b][h] = q[b]·W1[h] + W1_b[h] + W2_b[h]
__global__ __launch_bounds__(256) void k_prep(const float* __restrict__ w2,
                                              unsigned short* __restrict__ w2b,
                                              const float* __restrict__ q,
                                              const float* __restrict__ w1,
                                              const float* __restrict__ w1b,
                                              const float* __restrict__ w2bias,
                                              float* __restrict__ hidden) {
    const int bid = blockIdx.x;
    const int t = threadIdx.x;
    if (bid < 1280) {
        int i = (bid * 256 + t) * 4;
        f32x4 v = *(const f32x4*)(w2 + i);
        u16x4 o;
#pragma unroll
        for (int c = 0; c < 4; ++c) o[c] = bfbits(v[c]);
        *(u16x4*)(w2b + i) = o;
        return;
    }
    const int h = bid - 1280;
    __shared__ __align__(16) float w[1024];
    __shared__ float red[256];
    *(f32x4*)&w[t * 4] = *(const f32x4*)(w1 + (size_t)h * 1024 + t * 4);
    __syncthreads();
    const int b = t & 31, seg = t >> 5;
    const f32x4* q4 = (const f32x4*)(q + (size_t)b * 1024 + seg * 128);
    f32x4 accv = (f32x4){0.f, 0.f, 0.f, 0.f};
#pragma unroll 4
    for (int i = 0; i < 32; ++i) {
        f32x4 qv = q4[i];
        f32x4 wv = *(f32x4*)&w[seg * 128 + i * 4];
#pragma unroll
        for (int c = 0; c < 4; ++c) accv[c] = fmaf(qv[c], wv[c], accv[c]);
    }
    red[t] = accv[0] + accv[1] + accv[2] + accv[3];
    __syncthreads();
    if (t < 32) {
        float tot = 0.f;
#pragma unroll
        for (int sg = 0; sg < 8; ++sg) tot += red[sg * 32 + t];
        hidden[(size_t)t * 1024 + h] = tot + w1b[h] + w2bias[h];
    }
}

// ---------------- K2: 256x256, BK=64, fused fp32-A conversion (reg-staged) ----------------
// 8 waves (2M x 4N). LDS A/B: row-major [256][64] bf16, 2 K-tile dbuf, XOR slot
// swizzle (r9-proven). A staged from FP32 keys: per wave per tile 8
// global_load_dwordx4 -> regs, vmcnt(4)-drain AFTER the MFMA section, in-reg
// cvt to bf16, 4 ds_write_b128 to the pre-swizzled linear layout (identical
// bytes to the old keysbf path). B staged via global_load_lds from w2bf.
// WAR: writes target the other buffer, published by the end-of-tile
// lgkm(0)+vmcnt(0)+barrier (same as r9). grid 1024 (256 rt x 4 ht), block 512.
__global__ __launch_bounds__(512, 2) void k_score_bf(const float* __restrict__ keys,
                                                     const unsigned short* __restrict__ w2bf,
                                                     const float* __restrict__ hidden,
                                                     const float* __restrict__ va,
                                                     float* __restrict__ spart) {
    __shared__ __align__(16) __bf16 As[32768];  // 2 x [256][64] = 64KB
    __shared__ __align__(16) __bf16 Bs[32768];  // 64KB
    __shared__ float sred[1024];                // [256 rows][4 wc]

    const int t = threadIdx.x;
    const int lane = t & 63, wid = t >> 6;
    const int wr = wid >> 2, wc = wid & 3;
    const int pl = lane >> 4, r0 = lane & 15;

    // Bijective XCD swizzle, nwg=1024 (%8==0): XCD x owns rt in [x*32,(x+1)*32),
    // ht fastest (full w2bf + A-panel L2 reuse per XCD).
    const int bid = blockIdx.x;
    const int v = (bid & 7) * 128 + (bid >> 3);
    const int rt = v >> 2;  // 256 row tiles
    const int ht = v & 3;   // 4 col tiles

    // Epilogue constants loaded first (oldest vmem; drained by the prologue vmcnt(4)).
    const int b = rt >> 3;
    float hv[4], vav[4];
#pragma unroll
    for (int n = 0; n < 4; ++n) {
        int h = ht * 256 + wc * 64 + n * 16 + r0;
        hv[n] = hidden[(size_t)b * 1024 + h];
        vav[n] = va[h];
    }

    // ---- Staging addressing (coalesced): wave wid stages rows wid*32..+31.
    const int srow = wid * 32 + (lane >> 3);               // row within tile (j=0)
    const int sseg = (lane & 7) ^ ((lane >> 3) & 7);       // pre-swizzled 16B(bf16) segment
    const float* pAf = keys + (size_t)(rt * 256 + srow) * 1280 + sseg * 8;  // fp32 elems
    const unsigned short* pB = w2bf + (size_t)(ht * 256 + srow) * 1280 + sseg * 8;
    const int sdst = wid * 4096 + lane * 16;               // byte offset, + j*1024

    // ---- ds_read: element = BUF*16384 + row*64 + slot(ks)*8,
    // slot(ks) = ((ks*4+pl) ^ (row&7)); row&7 == r0&7 for all fragments.
    const int r7 = r0 & 7;
    const int sw0 = ((0 * 4 + pl) ^ r7) * 8;
    const int sw1 = ((1 * 4 + pl) ^ r7) * 8;
    const int aBase = (wr * 128 + r0) * 64;
    const int bBase = (wc * 64 + r0) * 64;

    f32x4 acc[8][4];
#pragma unroll
    for (int m = 0; m < 8; ++m)
#pragma unroll
        for (int n = 0; n < 4; ++n) acc[m][n] = (f32x4){0.f, 0.f, 0.f, 0.f};

    f32x4 af0[4], af1[4];  // A staging registers (8 dwordx4)

    // KOFF = k-tile element offset (kt*64), same for fp32/bf16 (element count).
#define LD_A(KOFF)                                                                   \
    do {                                                                             \
        _Pragma("unroll") for (int j = 0; j < 4; ++j) {                              \
            af0[j] = *(const f32x4*)(pAf + (KOFF) + j * (8 * 1280));                 \
            af1[j] = *(const f32x4*)(pAf + (KOFF) + j * (8 * 1280) + 4);             \
        }                                                                            \
    } while (0)
#define CVT_WR_A(NXT)                                                                \
    do {                                                                             \
        _Pragma("unroll") for (int j = 0; j < 4; ++j) {                              \
            u16x8 o;                                                                 \
            _Pragma("unroll") for (int c = 0; c < 4; ++c) {                          \
                o[c] = bfbits(af0[j][c]);                                            \
                o[c + 4] = bfbits(af1[j][c]);                                        \
            }                                                                        \
            *(u16x8*)((char*)As + (NXT) * 32768 + sdst + j * 1024) = o;              \
        }                                                                            \
    } while (0)
#define ST_B(NXT, KOFF)                                                              \
    do {                                                                             \
        _Pragma("unroll") for (int j = 0; j < 4; ++j)                                \
            load_lds16(pB + (KOFF) + j * (8 * 1280),                                 \
                       (char*)Bs + (NXT) * 32768 + sdst + j * 1024);                 \
    } while (0)

#define RD_B(DST, CUR, KS)                                                           \
    _Pragma("unroll") for (int n = 0; n < 4; ++n)                                    \
        DST[n] = *(bf16x8*)&Bs[(CUR) * 16384 + bBase + n * (16 * 64) +               \
                               ((KS) ? sw1 : sw0)];
#define RD_A(DST, CUR, KS, MH)                                                       \
    _Pragma("unroll") for (int mm = 0; mm < 4; ++mm)                                 \
        DST[mm] = *(bf16x8*)&As[(CUR) * 16384 + aBase + (MH) * (64 * 64) +           \
                                mm * (16 * 64) + ((KS) ? sw1 : sw0)];
#define MM(AV, BV, MH)                                                               \
    do {                                                                             \
        __builtin_amdgcn_s_setprio(1);                                               \
        _Pragma("unroll") for (int mm = 0; mm < 4; ++mm)                             \
            _Pragma("unroll") for (int n = 0; n < 4; ++n)                            \
                acc[(MH) * 4 + mm][n] = __builtin_amdgcn_mfma_f32_16x16x32_bf16(     \
                    AV[mm], BV[n], acc[(MH) * 4 + mm][n], 0, 0, 0);                  \
        __builtin_amdgcn_s_setprio(0);                                               \
    } while (0)

    // One K-tile: issue A-reg loads + B gload_lds for t+1, compute t, then
    // vmcnt(4) (drains A regs; B's 4 gload_lds newer), cvt+ds_write A,
    // lgkm(0)+vmcnt(0)+barrier (publish A writes + B lands + WAR guard).
#define TILE(CUR, NXT, KOFF, DOST, LAST)                                             \
    do {                                                                             \
        if (DOST) { LD_A(KOFF); ST_B(NXT, KOFF); }                                   \
        bf16x8 b0v[4], ax[4], ay[4];                                                 \
        RD_B(b0v, CUR, 0);                                                           \
        RD_A(ax, CUR, 0, 0);                                                         \
        RD_A(ay, CUR, 0, 1);                                                         \
        MM(ax, b0v, 0);                                                              \
        MM(ay, b0v, 1);                                                              \
        bf16x8 b1v[4], ax2[4], ay2[4];                                               \
        RD_B(b1v, CUR, 1);                                                           \
        RD_A(ax2, CUR, 1, 0);                                                        \
        RD_A(ay2, CUR, 1, 1);                                                        \
        MM(ax2, b1v, 0);                                                             \
        MM(ay2, b1v, 1);                                                             \
        if (DOST) {                                                                  \
            asm volatile("s_waitcnt vmcnt(4)" ::: "memory");                         \
            CVT_WR_A(NXT);                                                           \
        }                                                                            \
        if (!(LAST)) {                                                               \
            asm volatile("s_waitcnt vmcnt(0) lgkmcnt(0)" ::: "memory");              \
            __builtin_amdgcn_s_barrier();                                            \
        }                                                                            \
    } while (0)

    // Prologue: stage T0 (A via regs, B via gload_lds), publish.
    LD_A(0);
    ST_B(0, 0);
    asm volatile("s_waitcnt vmcnt(4)" ::: "memory");  // drains hv/vav + A regs
    CVT_WR_A(0);
    asm volatile("s_waitcnt vmcnt(0) lgkmcnt(0)" ::: "memory");
    __builtin_amdgcn_s_barrier();

    int koff = 64;  // element offset of the tile being staged (kt*64)
    for (int t2 = 0; t2 < 9; ++t2) {
        TILE(0, 1, koff, 1, 0);
        koff += 64;
        TILE(1, 0, koff, 1, 0);
        koff += 64;
    }
    TILE(0, 1, koff, 1, 0);  // tile 18, stages T19 (koff = 19*64)
    TILE(1, 0, 0, 0, 1);     // tile 19: no staging, no trailing sync
#undef TILE
#undef MM
#undef RD_A
#undef RD_B
#undef ST_B
#undef CVT_WR_A
#undef LD_A

    // Epilogue: relu(enc + hidden')*Va, reduce over this tile's 256 h.
#pragma unroll
    for (int m = 0; m < 8; ++m) {
#pragma unroll
        for (int j = 0; j < 4; ++j) {
            float s = 0.f;
#pragma unroll
            for (int n = 0; n < 4; ++n) {
                float v2 = acc[m][n][j] + hv[n];  // C/D: col=lane&15, row=(lane>>4)*4+j
                v2 = fmaxf(v2, 0.f);
                s = fmaf(v2, vav[n], s);
            }
            s += __shfl_xor(s, 1);
            s += __shfl_xor(s, 2);
            s += __shfl_xor(s, 4);
            s += __shfl_xor(s, 8);
            if (r0 == 0) sred[(wr * 128 + m * 16 + pl * 4 + j) * 4 + wc] = s;
        }
    }
    __syncthreads();
    if (t < 256)
        spart[(size_t)ht * 65536 + rt * 256 + t] =
            (sred[t * 4] + sred[t * 4 + 1]) + (sred[t * 4 + 2] + sred[t * 4 + 3]);
}

// ---------------- K3: softmax (4 partials) ----------------
__global__ __launch_bounds__(256) void k_softmax4(const float* __restrict__ spart,
                                                  float* __restrict__ wout) {
    const int b = blockIdx.x, t = threadIdx.x;
    __shared__ float red[256];
    float s[8];
#pragma unroll
    for (int i = 0; i < 8; ++i) {
        int l = t + i * 256;
        float v = 0.f;
#pragma unroll
        for (int ht = 0; ht < 4; ++ht) v += spart[(size_t)ht * 65536 + b * 2048 + l];
        s[i] = v;
    }
    float mx = s[0];
#pragma unroll
    for (int i = 1; i < 8; ++i) mx = fmaxf(mx, s[i]);
    red[t] = mx;
    __syncthreads();
    for (int st = 128; st > 0; st >>= 1) {
        if (t < st) red[t] = fmaxf(red[t], red[t + st]);
        __syncthreads();
    }
    mx = red[0];
    __syncthreads();
    float e[8];
    float sum = 0.f;
#pragma unroll
    for (int i = 0; i < 8; ++i) {
        e[i] = __expf(s[i] - mx);
        sum += e[i];
    }
    red[t] = sum;
    __syncthreads();
    for (int st = 128; st > 0; st >>= 1) {
        if (t < st) red[t] += red[t + st];
        __syncthreads();
    }
    float inv = 1.0f / red[0];
#pragma unroll
    for (int i = 0; i < 8; ++i) wout[(size_t)b * 2048 + t + i * 256] = e[i] * inv;
}

// ---------------- K4: context partials (fp32 keys, round-1-verified) ----------------
__global__ __launch_bounds__(256) void k_ctxpart_f32(const float* __restrict__ keys,
                                                     const float* __restrict__ wts,
                                                     float* __restrict__ cpart) {
    const int b = blockIdx.x, lc = blockIdx.y, t = threadIdx.x;
    f32x4 acc0 = (f32x4){0.f, 0.f, 0.f, 0.f};
    f32x4 acc1 = (f32x4){0.f, 0.f, 0.f, 0.f};
    const int l0 = lc * 128;
    const float* kb = keys + ((size_t)b * 2048 + l0) * 1280;
    const float* wb = wts + (size_t)b * 2048 + l0;
    for (int l = 0; l < 128; ++l) {
        float w = wb[l];
        const f32x4* kr = (const f32x4*)(kb + (size_t)l * 1280);
        f32x4 v = kr[t];
#pragma unroll
        for (int ci = 0; ci < 4; ++ci) acc0[ci] = fmaf(v[ci], w, acc0[ci]);
        if (t < 64) {
            f32x4 v2 = kr[256 + t];
#pragma unroll
            for (int ci = 0; ci < 4; ++ci) acc1[ci] = fmaf(v2[ci], w, acc1[ci]);
        }
    }
    float* cp = cpart + ((size_t)lc * 32 + b) * 1280;
    *(f32x4*)(cp + 4 * t) = acc0;
    if (t < 64) *(f32x4*)(cp + 1024 + 4 * t) = acc1;
}

__global__ __launch_bounds__(256) void k_ctxred16(const float* __restrict__ cpart,
                                                  float* __restrict__ ctx) {
    const int idx = blockIdx.x * 256 + threadIdx.x;  // < 40960
    const int b = idx / 1280, k = idx % 1280;
    float s = 0.f;
#pragma unroll
    for (int lc = 0; lc < 16; ++lc) s += cpart[((size_t)lc * 32 + b) * 1280 + k];
    ctx[(size_t)b * 1280 + k] = s;
}

extern "C" void kernel_launch(void* const* d_in, const int* in_sizes, int n_in,
                              void* d_out, int out_size, void* d_ws, size_t ws_size,
                              hipStream_t stream) {
    const float* query = (const float*)d_in[0];
    const float* keys = (const float*)d_in[1];
    const float* W1_w = (const float*)d_in[2];
    const float* W1_b = (const float*)d_in[3];
    const float* W2_w = (const float*)d_in[4];
    const float* W2_b = (const float*)d_in[5];
    const float* Va_w = (const float*)d_in[6];
    // Va_b cancels in softmax.

    float* out = (float*)d_out;
    float* ctx = out;            // [32][1280]
    float* wts = out + NB * NK;  // [32][2048]

    // Workspace (requires ~6.5 MB):
    char* ws = (char*)d_ws;
    float* hidden = (float*)ws;                             // 131072 B
    unsigned short* w2bf = (unsigned short*)(ws + 131072);  // 2621440 B
    float* spart = (float*)(ws + 2752512);                  // 4*65536*4 = 1048576 B
    float* cpart = (float*)(ws + 3801088);                  // 16*32*1280*4 = 2621440 B
    (void)ws_size;

    k_prep<<<2304, 256, 0, stream>>>(W2_w, w2bf, query, W1_w, W1_b, W2_b, hidden);
    k_score_bf<<<1024, 512, 0, stream>>>(keys, w2bf, hidden, Va_w, spart);
    k_softmax4<<<32, 256, 0, stream>>>(spart, wts);
    k_ctxpart_f32<<<dim3(32, 16), 256, 0, stream>>>(keys, wts, cpart);
    k_ctxred16<<<160, 256, 0, stream>>>(cpart, ctx);
}

// Round 16
// 318.511 us; speedup vs baseline: 1.2402x; 1.1553x over previous
//
#include <hip/hip_runtime.h>
#include <hip/hip_bf16.h>
#include <cstdint>
#include <cstddef>

// Problem constants
#define NB 32
#define NL 2048
#define NH 1024
#define NK 1280

typedef __bf16 bf16x8 __attribute__((ext_vector_type(8)));
typedef short short8 __attribute__((ext_vector_type(8)));
typedef float f32x4 __attribute__((ext_vector_type(4)));
typedef unsigned short u16x4 __attribute__((ext_vector_type(4)));
typedef unsigned short u16x8 __attribute__((ext_vector_type(8)));

__device__ __forceinline__ float bfbits2f(unsigned short b) {
    union { unsigned int u; float f; } v;
    v.u = ((unsigned int)b) << 16;
    return v.f;
}

__device__ __forceinline__ void load_lds16(const void* g, void* l) {
    __builtin_amdgcn_global_load_lds((const __attribute__((address_space(1))) void*)g,
                                     (__attribute__((address_space(3))) void*)l, 16, 0, 0);
}

// ---------------- K0: fused cvt — keys fp32->bf16 (blocks 0..40959) and
// W2_w fp32 [1024][1280]->bf16 (blocks 40960..42239) ----------------
__global__ __launch_bounds__(256) void k_cvt(const float* __restrict__ keys,
                                             unsigned short* __restrict__ kb,
                                             const float* __restrict__ w2,
                                             unsigned short* __restrict__ w2b) {
    const int bid = blockIdx.x;
    if (bid < 40960) {
        size_t i = ((size_t)bid * 256 + threadIdx.x) * 8;
        f32x4 v0 = *(const f32x4*)(keys + i);
        f32x4 v1 = *(const f32x4*)(keys + i + 4);
        u16x8 o;
#pragma unroll
        for (int c = 0; c < 4; ++c) {
            o[c] = __builtin_bit_cast(unsigned short, (__bf16)v0[c]);
            o[c + 4] = __builtin_bit_cast(unsigned short, (__bf16)v1[c]);
        }
        *(u16x8*)(kb + i) = o;
    } else {
        int i = ((bid - 40960) * 256 + threadIdx.x) * 4;
        f32x4 v = *(const f32x4*)(w2 + i);
        u16x4 o;
#pragma unroll
        for (int c = 0; c < 4; ++c) o[c] = __builtin_bit_cast(unsigned short, (__bf16)v[c]);
        *(u16x4*)(w2b + i) = o;
    }
}

__global__ __launch_bounds__(256) void k_w2cvt(const float* __restrict__ w2,
                                               unsigned short* __restrict__ w2b) {
    int i = (blockIdx.x * 256 + threadIdx.x) * 4;
    f32x4 v = *(const f32x4*)(w2 + i);
    u16x4 o;
#pragma unroll
    for (int c = 0; c < 4; ++c) o[c] = __builtin_bit_cast(unsigned short, (__bf16)v[c]);
    *(u16x4*)(w2b + i) = o;
}

// ---------------- K1: hidden ----------------
__global__ __launch_bounds__(256) void k_hidden(const float* __restrict__ q,
                                                const float* __restrict__ w1,
                                                const float* __restrict__ w1b,
                                                const float* __restrict__ w2b,
                                                float* __restrict__ hidden) {
    const int t = threadIdx.x;
    const int h = blockIdx.x;
    __shared__ __align__(16) float w[1024];
    __shared__ float red[256];
    *(f32x4*)&w[t * 4] = *(const f32x4*)(w1 + (size_t)h * 1024 + t * 4);
    __syncthreads();
    const int b = t & 31, seg = t >> 5;
    const f32x4* q4 = (const f32x4*)(q + (size_t)b * 1024 + seg * 128);
    f32x4 accv = (f32x4){0.f, 0.f, 0.f, 0.f};
#pragma unroll 4
    for (int i = 0; i < 32; ++i) {
        f32x4 qv = q4[i];
        f32x4 wv = *(f32x4*)&w[seg * 128 + i * 4];
#pragma unroll
        for (int c = 0; c < 4; ++c) accv[c] = fmaf(qv[c], wv[c], accv[c]);
    }
    red[t] = accv[0] + accv[1] + accv[2] + accv[3];
    __syncthreads();
    if (t < 32) {
        float tot = 0.f;
#pragma unroll
        for (int sg = 0; sg < 8; ++sg) tot += red[sg * 32 + t];
        hidden[(size_t)t * 1024 + h] = tot + w1b[h] + w2b[h];
    }
}

// ---------------- K2: 256x256, BK=64, coalesced staging + XOR-swizzled LDS (round-9 proven) ----------------
// BM=BN=256, BK=64, 8 waves (2M x 4N). LDS A/B: row-major [256][64] bf16
// (128B rows), 2 K-tile dbuf. Staging chunk = 8 rows x 128B: lane l fetches
// row c*8+(l>>3), 16B-seg (l&7)^(l>>3) -> 8 cache lines/instr (coalesced),
// linear LDS dest. ds_read: byte = row*128 + (((ks*4+pl)^(row&7))*16) —
// same involution, uniform bank load. One vmcnt(0)+barrier per K-tile.
// grid 1024 (256 rt x 4 ht), block 512.
__global__ __launch_bounds__(512, 2) void k_score_bf(const unsigned short* __restrict__ keysbf,
                                                     const unsigned short* __restrict__ w2bf,
                                                     const float* __restrict__ hidden,
                                                     const float* __restrict__ va,
                                                     float* __restrict__ spart) {
    __shared__ __align__(16) __bf16 As[32768];  // 2 x [256][64] = 64KB
    __shared__ __align__(16) __bf16 Bs[32768];  // 64KB
    __shared__ float sred[1024];                // [256 rows][4 wc]

    const int t = threadIdx.x;
    const int lane = t & 63, wid = t >> 6;
    const int wr = wid >> 2, wc = wid & 3;
    const int pl = lane >> 4, r0 = lane & 15;

    // Bijective XCD swizzle, nwg=1024 (%8==0): XCD x owns rt in [x*32,(x+1)*32),
    // ht fastest (full w2bf + A-panel L2 reuse per XCD).
    const int bid = blockIdx.x;
    const int v = (bid & 7) * 128 + (bid >> 3);
    const int rt = v >> 2;  // 256 row tiles (256 rows, same batch: 8 tiles/batch)
    const int ht = v & 3;   // 4 col tiles (256 h)

    // Epilogue constants loaded first (oldest vmem, drained long before staging).
    const int b = rt >> 3;
    float hv[4], vav[4];
#pragma unroll
    for (int n = 0; n < 4; ++n) {
        int h = ht * 256 + wc * 64 + n * 16 + r0;
        hv[n] = hidden[(size_t)b * 1024 + h];
        vav[n] = va[h];
    }

    // ---- Staging addressing (coalesced): wave wid stages rows wid*32..+31.
    const int srow = wid * 32 + (lane >> 3);               // global row within tile
    const int sseg = (lane & 7) ^ ((lane >> 3) & 7);       // pre-swizzled 16B segment
    const unsigned short* pA = keysbf + (size_t)(rt * 256 + srow) * 1280 + sseg * 8;
    const unsigned short* pB = w2bf + (size_t)(ht * 256 + srow) * 1280 + sseg * 8;
    const int sdst = wid * 4096 + lane * 16;               // byte offset of chunk j=0, +j*1024

    // ---- ds_read addressing: element = BUF*16384 + row*64 + slot(ks)*8,
    // slot(ks) = ((ks*4+pl) ^ (row&7)); row&7 == r0&7 for all fragments.
    const int r7 = r0 & 7;
    const int sw0 = (((0 * 4 + pl) ^ r7)) * 8;  // ks=0 slot, elements
    const int sw1 = (((1 * 4 + pl) ^ r7)) * 8;  // ks=1 slot, elements
    const int aBase = (wr * 128 + r0) * 64;
    const int bBase = (wc * 64 + r0) * 64;

    f32x4 acc[8][4];
#pragma unroll
    for (int m = 0; m < 8; ++m)
#pragma unroll
        for (int n = 0; n < 4; ++n) acc[m][n] = (f32x4){0.f, 0.f, 0.f, 0.f};

    // NXT = buffer (0/1), KOFF = k-tile element offset (kt*64).
#define ST_A(NXT, KOFF)                                                              \
    do {                                                                             \
        _Pragma("unroll") for (int j = 0; j < 4; ++j)                                \
            load_lds16(pA + (KOFF) + j * (8 * 1280),                                 \
                       (char*)As + (NXT) * 32768 + sdst + j * 1024);                 \
    } while (0)
#define ST_B(NXT, KOFF)                                                              \
    do {                                                                             \
        _Pragma("unroll") for (int j = 0; j < 4; ++j)                                \
            load_lds16(pB + (KOFF) + j * (8 * 1280),                                 \
                       (char*)Bs + (NXT) * 32768 + sdst + j * 1024);                 \
    } while (0)

#define RD_B(DST, CUR, KS)                                                           \
    _Pragma("unroll") for (int n = 0; n < 4; ++n)                                    \
        DST[n] = *(bf16x8*)&Bs[(CUR) * 16384 + bBase + n * (16 * 64) +               \
                               ((KS) ? sw1 : sw0)];
#define RD_A(DST, CUR, KS, MH)                                                       \
    _Pragma("unroll") for (int mm = 0; mm < 4; ++mm)                                 \
        DST[mm] = *(bf16x8*)&As[(CUR) * 16384 + aBase + (MH) * (64 * 64) +           \
                                mm * (16 * 64) + ((KS) ? sw1 : sw0)];
#define MM(AV, BV, MH)                                                               \
    do {                                                                             \
        __builtin_amdgcn_s_setprio(1);                                               \
        _Pragma("unroll") for (int mm = 0; mm < 4; ++mm)                             \
            _Pragma("unroll") for (int n = 0; n < 4; ++n)                            \
                acc[(MH) * 4 + mm][n] = __builtin_amdgcn_mfma_f32_16x16x32_bf16(     \
                    AV[mm], BV[n], acc[(MH) * 4 + mm][n], 0, 0, 0);                  \
        __builtin_amdgcn_s_setprio(0);                                               \
    } while (0)

    // One K-tile, single trailing vmcnt(0)+barrier. Interior compiler-scheduled.
#define TILE(CUR, NXT, KOFF, DOST, LAST)                                             \
    do {                                                                             \
        if (DOST) ST_A(NXT, KOFF);                                                   \
        bf16x8 b0v[4], ax[4], ay[4];                                                 \
        RD_B(b0v, CUR, 0);                                                           \
        RD_A(ax, CUR, 0, 0);                                                         \
        RD_A(ay, CUR, 0, 1);                                                         \
        MM(ax, b0v, 0);                                                              \
        MM(ay, b0v, 1);                                                              \
        if (DOST) ST_B(NXT, KOFF);                                                   \
        bf16x8 b1v[4], ax2[4], ay2[4];                                               \
        RD_B(b1v, CUR, 1);                                                           \
        RD_A(ax2, CUR, 1, 0);                                                        \
        RD_A(ay2, CUR, 1, 1);                                                        \
        MM(ax2, b1v, 0);                                                             \
        MM(ay2, b1v, 1);                                                             \
        if (!(LAST)) {                                                               \
            asm volatile("s_waitcnt vmcnt(0)" ::: "memory");                         \
            __builtin_amdgcn_s_barrier();                                            \
        }                                                                            \
    } while (0)

    // Prologue: stage T0 fully, drain, publish.
    ST_A(0, 0);
    ST_B(0, 0);
    asm volatile("s_waitcnt vmcnt(0)" ::: "memory");
    __builtin_amdgcn_s_barrier();

    int koff = 64;  // element offset of the tile being staged (kt*64)
    for (int t2 = 0; t2 < 9; ++t2) {
        TILE(0, 1, koff, 1, 0);
        koff += 64;
        TILE(1, 0, koff, 1, 0);
        koff += 64;
    }
    TILE(0, 1, koff, 1, 0);  // tile 18, stages T19 (koff = 19*64)
    TILE(1, 0, 0, 0, 1);     // tile 19: no staging, no trailing sync
#undef TILE
#undef MM
#undef RD_A
#undef RD_B
#undef ST_A
#undef ST_B

    // Epilogue: relu(enc + hidden')*Va, reduce over this tile's 256 h.
#pragma unroll
    for (int m = 0; m < 8; ++m) {
#pragma unroll
        for (int j = 0; j < 4; ++j) {
            float s = 0.f;
#pragma unroll
            for (int n = 0; n < 4; ++n) {
                float v2 = acc[m][n][j] + hv[n];  // C/D: col=lane&15, row=(lane>>4)*4+j
                v2 = fmaxf(v2, 0.f);
                s = fmaf(v2, vav[n], s);
            }
            s += __shfl_xor(s, 1);
            s += __shfl_xor(s, 2);
            s += __shfl_xor(s, 4);
            s += __shfl_xor(s, 8);
            if (r0 == 0) sred[(wr * 128 + m * 16 + pl * 4 + j) * 4 + wc] = s;
        }
    }
    __syncthreads();
    if (t < 256)
        spart[(size_t)ht * 65536 + rt * 256 + t] =
            (sred[t * 4] + sred[t * 4 + 1]) + (sred[t * 4 + 2] + sred[t * 4 + 3]);
}

// ---------------- K2 fallback (fp32 keys, round-1 structure, 8 ht partials) ----------------
#define LOAD_AB(IT)                                        \
    do {                                                   \
        const float* ap_ = aptr + (IT) * 32;               \
        a0 = *(const f32x4*)(ap_);                         \
        a1 = *(const f32x4*)(ap_ + 4);                     \
        a2 = *(const f32x4*)(ap_ + 8);                     \
        a3 = *(const f32x4*)(ap_ + 12);                    \
        const unsigned short* bp_ = bptr + (IT) * 32;      \
        b0 = *(const short8*)(bp_);                        \
        b1 = *(const short8*)(bp_ + 8);                    \
    } while (0)

__global__ __launch_bounds__(256, 2) void k_score_f32(const float* __restrict__ keys,
                                                      const unsigned short* __restrict__ w2bf,
                                                      const float* __restrict__ hidden,
                                                      const float* __restrict__ va,
                                                      float* __restrict__ spart) {
    __shared__ __align__(16) __bf16 As[4096];
    __shared__ __align__(16) __bf16 Bs[4096];
    __shared__ float sred[256];
    const int t = threadIdx.x;
    const int rt = blockIdx.x, ht = blockIdx.y;
    const int row = t >> 1, half = t & 1;
    const float* aptr = keys + (size_t)(rt * 128 + row) * 1280 + half * 16;
    const unsigned short* bptr = w2bf + (size_t)(ht * 128 + row) * 1280 + half * 16;
    const int wA0 = (2 * half) * 1024 + row * 8;
    const int wA1 = wA0 + 1024;
    f32x4 acc[4][4];
#pragma unroll
    for (int m = 0; m < 4; ++m)
#pragma unroll
        for (int n = 0; n < 4; ++n) acc[m][n] = (f32x4){0.f, 0.f, 0.f, 0.f};
    const int lane = t & 63, wid = t >> 6;
    const int wr = wid >> 1, wc = wid & 1;
    const int pl = lane >> 4, r0 = lane & 15;
    const int aroff = pl * 1024 + (wr * 64 + r0) * 8;
    const int broff = pl * 1024 + (wc * 64 + r0) * 8;
    f32x4 a0, a1, a2, a3;
    short8 b0, b1;
    LOAD_AB(0);
    for (int it = 0; it < 40; ++it) {
        __syncthreads();
        bf16x8 p0, p1;
#pragma unroll
        for (int e = 0; e < 4; ++e) {
            p0[e] = (__bf16)a0[e];
            p0[e + 4] = (__bf16)a1[e];
            p1[e] = (__bf16)a2[e];
            p1[e + 4] = (__bf16)a3[e];
        }
        *(bf16x8*)&As[wA0] = p0;
        *(bf16x8*)&As[wA1] = p1;
        *(short8*)&Bs[wA0] = b0;
        *(short8*)&Bs[wA1] = b1;
        __syncthreads();
        if (it + 1 < 40) LOAD_AB(it + 1);
        bf16x8 af[4], bfv[4];
#pragma unroll
        for (int m = 0; m < 4; ++m) af[m] = *(bf16x8*)&As[aroff + m * 128];
#pragma unroll
        for (int n = 0; n < 4; ++n) bfv[n] = *(bf16x8*)&Bs[broff + n * 128];
#pragma unroll
        for (int m = 0; m < 4; ++m)
#pragma unroll
            for (int n = 0; n < 4; ++n)
                acc[m][n] = __builtin_amdgcn_mfma_f32_16x16x32_bf16(af[m], bfv[n], acc[m][n], 0, 0, 0);
    }
    const int b = rt >> 4;
    float hv[4], vav[4];
#pragma unroll
    for (int n = 0; n < 4; ++n) {
        int h = ht * 128 + wc * 64 + n * 16 + r0;
        hv[n] = hidden[(size_t)b * 1024 + h];
        vav[n] = va[h];
    }
#pragma unroll
    for (int m = 0; m < 4; ++m) {
#pragma unroll
        for (int j = 0; j < 4; ++j) {
            float s = 0.f;
#pragma unroll
            for (int n = 0; n < 4; ++n) {
                float v = acc[m][n][j] + hv[n];
                v = fmaxf(v, 0.f);
                s = fmaf(v, vav[n], s);
            }
            s += __shfl_xor(s, 1);
            s += __shfl_xor(s, 2);
            s += __shfl_xor(s, 4);
            s += __shfl_xor(s, 8);
            if (r0 == 0) sred[(wr * 64 + m * 16 + pl * 4 + j) * 2 + wc] = s;
        }
    }
    __syncthreads();
    if (t < 128) spart[(size_t)ht * 65536 + rt * 128 + t] = sred[t * 2] + sred[t * 2 + 1];
}

// ---------------- K3: softmax (4 partials, main path) ----------------
__global__ __launch_bounds__(256) void k_softmax4(const float* __restrict__ spart,
                                                  float* __restrict__ wout) {
    const int b = blockIdx.x, t = threadIdx.x;
    __shared__ float red[256];
    float s[8];
#pragma unroll
    for (int i = 0; i < 8; ++i) {
        int l = t + i * 256;
        float v = 0.f;
#pragma unroll
        for (int ht = 0; ht < 4; ++ht) v += spart[(size_t)ht * 65536 + b * 2048 + l];
        s[i] = v;
    }
    float mx = s[0];
#pragma unroll
    for (int i = 1; i < 8; ++i) mx = fmaxf(mx, s[i]);
    red[t] = mx;
    __syncthreads();
    for (int st = 128; st > 0; st >>= 1) {
        if (t < st) red[t] = fmaxf(red[t], red[t + st]);
        __syncthreads();
    }
    mx = red[0];
    __syncthreads();
    float e[8];
    float sum = 0.f;
#pragma unroll
    for (int i = 0; i < 8; ++i) {
        e[i] = __expf(s[i] - mx);
        sum += e[i];
    }
    red[t] = sum;
    __syncthreads();
    for (int st = 128; st > 0; st >>= 1) {
        if (t < st) red[t] += red[t + st];
        __syncthreads();
    }
    float inv = 1.0f / red[0];
#pragma unroll
    for (int i = 0; i < 8; ++i) wout[(size_t)b * 2048 + t + i * 256] = e[i] * inv;
}

// ---------------- K3b: softmax (8 partials, fallback path) ----------------
__global__ __launch_bounds__(256) void k_softmax8(const float* __restrict__ spart,
                                                  float* __restrict__ wout) {
    const int b = blockIdx.x, t = threadIdx.x;
    __shared__ float red[256];
    float s[8];
#pragma unroll
    for (int i = 0; i < 8; ++i) {
        int l = t + i * 256;
        float v = 0.f;
#pragma unroll
        for (int ht = 0; ht < 8; ++ht) v += spart[(size_t)ht * 65536 + b * 2048 + l];
        s[i] = v;
    }
    float mx = s[0];
#pragma unroll
    for (int i = 1; i < 8; ++i) mx = fmaxf(mx, s[i]);
    red[t] = mx;
    __syncthreads();
    for (int st = 128; st > 0; st >>= 1) {
        if (t < st) red[t] = fmaxf(red[t], red[t + st]);
        __syncthreads();
    }
    mx = red[0];
    __syncthreads();
    float e[8];
    float sum = 0.f;
#pragma unroll
    for (int i = 0; i < 8; ++i) {
        e[i] = __expf(s[i] - mx);
        sum += e[i];
    }
    red[t] = sum;
    __syncthreads();
    for (int st = 128; st > 0; st >>= 1) {
        if (t < st) red[t] += red[t + st];
        __syncthreads();
    }
    float inv = 1.0f / red[0];
#pragma unroll
    for (int i = 0; i < 8; ++i) wout[(size_t)b * 2048 + t + i * 256] = e[i] * inv;
}

// ---------------- K4 (bf16): context partials ----------------
__global__ __launch_bounds__(256) void k_ctx_bf(const unsigned short* __restrict__ keysbf,
                                                const float* __restrict__ wts,
                                                float* __restrict__ cpart) {
    const int b = blockIdx.x, kc = blockIdx.y, lc = blockIdx.z, t = threadIdx.x;
    const int c = t & 15, g = t >> 4;
    const unsigned short* kp = keysbf + ((size_t)b * 2048 + lc * 512 + g) * 1280 + kc * 128 + c * 8;
    const float* wb = wts + (size_t)b * 2048 + lc * 512 + g;
    float acc[8];
#pragma unroll
    for (int j = 0; j < 8; ++j) acc[j] = 0.f;
    for (int i = 0; i < 32; ++i) {
        u16x8 v = *(const u16x8*)kp;
        float w = *wb;
#pragma unroll
        for (int j = 0; j < 8; ++j) acc[j] = fmaf(w, bfbits2f(v[j]), acc[j]);
        kp += (size_t)16 * 1280;
        wb += 16;
    }
    __shared__ float sred[2048];
#pragma unroll
    for (int j = 0; j < 8; ++j) sred[t * 8 + j] = acc[j];
    __syncthreads();
    if (t < 128) {
        float s = 0.f;
#pragma unroll
        for (int g2 = 0; g2 < 16; ++g2) s += sred[g2 * 128 + t];
        cpart[((size_t)lc * 32 + b) * 1280 + kc * 128 + t] = s;
    }
}

__global__ __launch_bounds__(256) void k_ctxred4(const float* __restrict__ cpart,
                                                 float* __restrict__ ctx) {
    const int idx = blockIdx.x * 256 + threadIdx.x;  // < 40960
    const int b = idx / 1280, k = idx % 1280;
    float s = 0.f;
#pragma unroll
    for (int lc = 0; lc < 4; ++lc) s += cpart[((size_t)lc * 32 + b) * 1280 + k];
    ctx[(size_t)b * 1280 + k] = s;
}

// ---------------- K4/K5 fallback (fp32 keys) ----------------
__global__ __launch_bounds__(256) void k_ctxpart_f32(const float* __restrict__ keys,
                                                     const float* __restrict__ wts,
                                                     float* __restrict__ cpart) {
    const int b = blockIdx.x, lc = blockIdx.y, t = threadIdx.x;
    f32x4 acc0 = (f32x4){0.f, 0.f, 0.f, 0.f};
    f32x4 acc1 = (f32x4){0.f, 0.f, 0.f, 0.f};
    const int l0 = lc * 128;
    const float* kb = keys + ((size_t)b * 2048 + l0) * 1280;
    const float* wb = wts + (size_t)b * 2048 + l0;
    for (int l = 0; l < 128; ++l) {
        float w = wb[l];
        const f32x4* kr = (const f32x4*)(kb + (size_t)l * 1280);
        f32x4 v = kr[t];
#pragma unroll
        for (int ci = 0; ci < 4; ++ci) acc0[ci] = fmaf(v[ci], w, acc0[ci]);
        if (t < 64) {
            f32x4 v2 = kr[256 + t];
#pragma unroll
            for (int ci = 0; ci < 4; ++ci) acc1[ci] = fmaf(v2[ci], w, acc1[ci]);
        }
    }
    float* cp = cpart + ((size_t)lc * 32 + b) * 1280;
    *(f32x4*)(cp + 4 * t) = acc0;
    if (t < 64) *(f32x4*)(cp + 1024 + 4 * t) = acc1;
}

__global__ __launch_bounds__(256) void k_ctxred16(const float* __restrict__ cpart,
                                                  float* __restrict__ ctx) {
    const int idx = blockIdx.x * 256 + threadIdx.x;
    const int b = idx / 1280, k = idx % 1280;
    float s = 0.f;
#pragma unroll
    for (int lc = 0; lc < 16; ++lc) s += cpart[((size_t)lc * 32 + b) * 1280 + k];
    ctx[(size_t)b * 1280 + k] = s;
}

extern "C" void kernel_launch(void* const* d_in, const int* in_sizes, int n_in,
                              void* d_out, int out_size, void* d_ws, size_t ws_size,
                              hipStream_t stream) {
    const float* query = (const float*)d_in[0];
    const float* keys = (const float*)d_in[1];
    const float* W1_w = (const float*)d_in[2];
    const float* W1_b = (const float*)d_in[3];
    const float* W2_w = (const float*)d_in[4];
    const float* W2_b = (const float*)d_in[5];
    const float* Va_w = (const float*)d_in[6];
    // Va_b cancels in softmax.

    float* out = (float*)d_out;
    float* ctx = out;            // [32][1280]
    float* wts = out + NB * NK;  // [32][2048]

    char* ws = (char*)d_ws;
    float* hidden = (float*)ws;                             // 131072 B
    unsigned short* w2bf = (unsigned short*)(ws + 131072);  // 2621440 B
    float* spart = (float*)(ws + 2752512);                  // 2097152 B
    float* cpart = (float*)(ws + 4849664);                  // <= 2621440 B
    unsigned short* keysbf = (unsigned short*)(ws + 7471104);  // 167772160 B
    const bool big = ws_size >= (size_t)7471104 + 167772160;

    if (big) {
        k_cvt<<<42240, 256, 0, stream>>>(keys, keysbf, W2_w, w2bf);
        k_hidden<<<1024, 256, 0, stream>>>(query, W1_w, W1_b, W2_b, hidden);
        k_score_bf<<<1024, 512, 0, stream>>>(keysbf, w2bf, hidden, Va_w, spart);
        k_softmax4<<<32, 256, 0, stream>>>(spart, wts);
        k_ctx_bf<<<dim3(32, 10, 4), 256, 0, stream>>>(keysbf, wts, cpart);
        k_ctxred4<<<160, 256, 0, stream>>>(cpart, ctx);
    } else {
        k_w2cvt<<<1280, 256, 0, stream>>>(W2_w, w2bf);
        k_hidden<<<1024, 256, 0, stream>>>(query, W1_w, W1_b, W2_b, hidden);
        k_score_f32<<<dim3(512, 8), 256, 0, stream>>>(keys, w2bf, hidden, Va_w, spart);
        k_softmax8<<<32, 256, 0, stream>>>(spart, wts);
        k_ctxpart_f32<<<dim3(32, 16), 256, 0, stream>>>(keys, wts, cpart);
        k_ctxred16<<<160, 256, 0, stream>>>(cpart, ctx);
    }
}